// Round 25
// baseline (281.997 us; speedup 1.0000x reference)
//
#include <hip/hip_runtime.h>
#include <hip/hip_bf16.h>

typedef __hip_bfloat16 bf16;

constexpr int kB = 2, kT = 2048, kC = 1024, kNH = 16, kHS = 64;
constexpr int kL = 32, kST = 16, kWIN = 256;
constexpr int kNB = (kT - kL) / kST + 1;   // 127
constexpr int kM = kB * kT;                // 4096

typedef __attribute__((ext_vector_type(8))) short short8;   // bf16 MFMA A/B frag (4 VGPRs)
typedef __attribute__((ext_vector_type(4))) short short4v;
typedef __attribute__((ext_vector_type(4))) float f32x4;

__device__ __forceinline__ float b2f(bf16 v) { return __bfloat162float(v); }
__device__ __forceinline__ bf16  f2b(float v) { return __float2bfloat16(v); }
__device__ __forceinline__ float bu2f(unsigned int u) { return __uint_as_float(u << 16); }
__device__ __forceinline__ float gelu_f(float v) { return 0.5f * v * (1.0f + erff(v * 0.70710678118654752f)); }
// branchless tanh-form GELU (max |err| vs exact ~3e-4); used only in comp_mlp
__device__ __forceinline__ float gelu_fast(float v) {
  const float w = v * (1.5957691216f + 0.0713548162f * v * v);   // 2*sqrt(2/pi)*(v+0.044715v^3)
  return v * __builtin_amdgcn_rcpf(1.0f + __expf(-w));           // v * sigmoid(w)
}
__device__ __forceinline__ short fbits(float v) {
  return (short)__builtin_bit_cast(unsigned short, f2b(v));
}
// async global->LDS, 16 bytes per lane (dest = wave-uniform base + lane*16)
__device__ __forceinline__ void gl16(const bf16* g, bf16* l) {
  __builtin_amdgcn_global_load_lds(
      (const __attribute__((address_space(1))) void*)g,
      (__attribute__((address_space(3))) void*)l, 16, 0, 0);
}

// ---------------- fp32 -> bf16 conversion (vectorized, grid-stride) ----------------
__global__ __launch_bounds__(256) void f32_to_bf16(const float* __restrict__ src,
                                                   bf16* __restrict__ dst, int n4) {
  int i = blockIdx.x * 256 + threadIdx.x;
  const int stride = gridDim.x * 256;
  for (; i < n4; i += stride) {
    float4 v = ((const float4*)src)[i];
    short4v w; w.x = fbits(v.x); w.y = fbits(v.y); w.z = fbits(v.z); w.w = fbits(v.w);
    ((short4v*)dst)[i] = w;
  }
}

// ---------------- all-bf16 MFMA GEMM: 128x128 tile, BK=64, 8 waves (2x4) [R23-proven] ----------------
template<int EPI, typename TY>
__global__ __launch_bounds__(512) void gemm_bf16(
    const bf16* __restrict__ X, const bf16* __restrict__ W,
    const float* __restrict__ bias, TY* __restrict__ Y,
    int M, int N, int K, int nbx)
{
  __shared__ __align__(16) bf16 As[128 * 64];
  __shared__ __align__(16) bf16 Bs[128 * 64];
  const int nwg = gridDim.x;
  const int bid = blockIdx.x;
  const int swz = (bid & 7) * (nwg >> 3) + (bid >> 3);
  const int bm = (swz / nbx) * 128;
  const int bn = (swz % nbx) * 128;
  const int tid = threadIdx.x;
  const int lane = tid & 63;
  const int w = tid >> 6;
  const int wr = w >> 2, wc = w & 3;      // 2x4 wave grid; wave tile 64 x 32
  const int fr = lane & 15, q = lane >> 4;
  const int srow = lane >> 3;
  const int scol = (lane & 7) * 8;

  f32x4 acc[4][2];
#pragma unroll
  for (int i = 0; i < 4; ++i)
#pragma unroll
    for (int j = 0; j < 2; ++j) acc[i][j] = (f32x4){0.f, 0.f, 0.f, 0.f};

  const bf16* Xb = X + (size_t)bm * K;
  const bf16* Wb = W + (size_t)bn * K;

  for (int k0 = 0; k0 < K; k0 += 64) {
    __syncthreads();
#pragma unroll
    for (int i = 0; i < 2; ++i) {
      const int r = w * 16 + i * 8 + srow;
      const int sc = scol ^ ((r & 7) << 3);   // pre-swizzled global source chunk
      gl16(Xb + (size_t)r * K + k0 + sc, &As[r * 64 + scol]);
      gl16(Wb + (size_t)r * K + k0 + sc, &Bs[r * 64 + scol]);
    }
    __syncthreads();
#pragma unroll
    for (int kk = 0; kk < 2; ++kk) {
      short8 af[4], bfr[2];
#pragma unroll
      for (int i = 0; i < 4; ++i) {
        const int ar = wr * 64 + i * 16 + fr;
        af[i] = *reinterpret_cast<const short8*>(&As[ar * 64 + ((kk * 32 + q * 8) ^ ((ar & 7) << 3))]);
      }
#pragma unroll
      for (int j = 0; j < 2; ++j) {
        const int br = wc * 32 + j * 16 + fr;
        bfr[j] = *reinterpret_cast<const short8*>(&Bs[br * 64 + ((kk * 32 + q * 8) ^ ((br & 7) << 3))]);
      }
#pragma unroll
      for (int i = 0; i < 4; ++i)
#pragma unroll
        for (int j = 0; j < 2; ++j)
          acc[i][j] = __builtin_amdgcn_mfma_f32_16x16x32_bf16(af[i], bfr[j], acc[i][j], 0, 0, 0);
    }
  }

#pragma unroll
  for (int j = 0; j < 2; ++j) {
    const int gcol = bn + wc * 32 + j * 16 + fr;
    const float bv = bias[gcol];
#pragma unroll
    for (int i = 0; i < 4; ++i) {
      const int grow0 = bm + wr * 64 + i * 16 + q * 4;
#pragma unroll
      for (int r = 0; r < 4; ++r) {
        float v = acc[i][j][r] + bv;
        if (EPI == 1) v = gelu_f(v);
        if (EPI == 3) v = 1.f / (1.f + expf(-v));
        if constexpr (sizeof(TY) == 2) Y[(size_t)(grow0 + r) * N + gcol] = f2b(v);
        else                           ((float*)Y)[(size_t)(grow0 + r) * N + gcol] = v;
      }
    }
  }
}

// ---------------- small-tile GEMM: 64x64 tile, BK=128, 4 waves (2x2) ----------------
// Deep-K variant (gate, proj): halves barrier drains vs BK=64; LDS 32 KB -> still
// >= grid-limited 4 blocks/CU. Swizzle identical involution on 128-col rows
// (XOR flips bits 3-5 only; bit 6 preserved; staging & read use the same XOR).
template<int EPI, typename TY>
__global__ __launch_bounds__(256) void gemm_bf16_t64(
    const bf16* __restrict__ X, const bf16* __restrict__ W,
    const float* __restrict__ bias, TY* __restrict__ Y,
    int M, int N, int K, int nbx)
{
  __shared__ __align__(16) bf16 As[64 * 128];
  __shared__ __align__(16) bf16 Bs[64 * 128];
  const int nwg = gridDim.x;
  const int bid = blockIdx.x;
  const int swz = (bid & 7) * (nwg >> 3) + (bid >> 3);
  const int bm = (swz / nbx) * 64;
  const int bn = (swz % nbx) * 64;
  const int tid = threadIdx.x;
  const int lane = tid & 63;
  const int w = tid >> 6;                 // 0..3
  const int wr = w >> 1, wc = w & 1;      // 2x2 wave grid; wave tile 32 x 32
  const int fr = lane & 15, q = lane >> 4;
  const int srow = lane >> 4;             // 0..3 (row within 4-row stage group)
  const int scol = (lane & 15) * 8;       // 0..120 (col chunk within 128)

  f32x4 acc[2][2];
#pragma unroll
  for (int i = 0; i < 2; ++i)
#pragma unroll
    for (int j = 0; j < 2; ++j) acc[i][j] = (f32x4){0.f, 0.f, 0.f, 0.f};

  const bf16* Xb = X + (size_t)bm * K;
  const bf16* Wb = W + (size_t)bn * K;

  for (int k0 = 0; k0 < K; k0 += 128) {
    __syncthreads();
#pragma unroll
    for (int i = 0; i < 4; ++i) {        // wave w stages rows [w*16, w*16+16) of A and B
      const int r = w * 16 + i * 4 + srow;
      const int sc = scol ^ ((r & 7) << 3);
      gl16(Xb + (size_t)r * K + k0 + sc, &As[r * 128 + scol]);
      gl16(Wb + (size_t)r * K + k0 + sc, &Bs[r * 128 + scol]);
    }
    __syncthreads();
#pragma unroll
    for (int kk = 0; kk < 4; ++kk) {
      short8 af[2], bfr[2];
#pragma unroll
      for (int i = 0; i < 2; ++i) {
        const int ar = wr * 32 + i * 16 + fr;
        af[i] = *reinterpret_cast<const short8*>(&As[ar * 128 + ((kk * 32 + q * 8) ^ ((ar & 7) << 3))]);
      }
#pragma unroll
      for (int j = 0; j < 2; ++j) {
        const int br = wc * 32 + j * 16 + fr;
        bfr[j] = *reinterpret_cast<const short8*>(&Bs[br * 128 + ((kk * 32 + q * 8) ^ ((br & 7) << 3))]);
      }
#pragma unroll
      for (int i = 0; i < 2; ++i)
#pragma unroll
        for (int j = 0; j < 2; ++j)
          acc[i][j] = __builtin_amdgcn_mfma_f32_16x16x32_bf16(af[i], bfr[j], acc[i][j], 0, 0, 0);
    }
  }

#pragma unroll
  for (int j = 0; j < 2; ++j) {
    const int gcol = bn + wc * 32 + j * 16 + fr;
    const float bv = bias[gcol];
#pragma unroll
    for (int i = 0; i < 2; ++i) {
      const int grow0 = bm + wr * 32 + i * 16 + q * 4;
#pragma unroll
      for (int r = 0; r < 4; ++r) {
        float v = acc[i][j][r] + bv;
        if (EPI == 1) v = gelu_f(v);
        if (EPI == 3) v = 1.f / (1.f + expf(-v));
        if constexpr (sizeof(TY) == 2) Y[(size_t)(grow0 + r) * N + gcol] = f2b(v);
        else                           ((float*)Y)[(size_t)(grow0 + r) * N + gcol] = v;
      }
    }
  }
}

// ---------------- Compression MLP via MFMA (R22-proven: gelu_fast) ----------------
__global__ __launch_bounds__(256) void comp_mlp_mfma(
    const bf16* __restrict__ kvbuf,
    const float* __restrict__ k_fc1W, const float* __restrict__ k_fc1b,
    const float* __restrict__ k_fc2W, const float* __restrict__ k_fc2b,
    const float* __restrict__ k_rpW,  const float* __restrict__ k_rpb,
    const float* __restrict__ k_wpe,  bf16* __restrict__ k_out,
    const float* __restrict__ v_fc1W, const float* __restrict__ v_fc1b,
    const float* __restrict__ v_fc2W, const float* __restrict__ v_fc2b,
    const float* __restrict__ v_rpW,  const float* __restrict__ v_rpb,
    const float* __restrict__ v_wpe,  bf16* __restrict__ v_out)
{
  __shared__ __align__(16) short XPE[64 * 40];
  __shared__ __align__(16) short XU [64 * 40];
  __shared__ __align__(16) short FC1[128 * 40];
  __shared__ float s_fc1b[128];
  __shared__ float s_fc2W[128];
  __shared__ float s_rpW[32];
  const int tid = threadIdx.x;
  const int lane = tid & 63;
  const int w = tid >> 6;
  const int fr = lane & 15, q = lane >> 4;
  const int blk = blockIdx.x;
  const int h = blockIdx.y;
  const int s = blockIdx.z & 1;
  const int b = blockIdx.z >> 1;
  const int t0 = blk * kST;
  const float* fc1W = s ? v_fc1W : k_fc1W;
  const float* fc1b = s ? v_fc1b : k_fc1b;
  const float* fc2W = s ? v_fc2W : k_fc2W;
  const float* fc2b = s ? v_fc2b : k_fc2b;
  const float* rpW  = s ? v_rpW  : k_rpW;
  const float* rpb  = s ? v_rpb  : k_rpb;
  const float* wpe  = s ? v_wpe  : k_wpe;
  bf16* outp        = s ? v_out  : k_out;

  {
    const int base = tid * 16;
#pragma unroll
    for (int c = 0; c < 4; ++c) {
      float4 v = *reinterpret_cast<const float4*>(fc1W + base + c * 4);
      const int idx = base + c * 4;
      short* dst = &FC1[(idx >> 5) * 40 + (idx & 31)];
      dst[0] = fbits(v.x); dst[1] = fbits(v.y); dst[2] = fbits(v.z); dst[3] = fbits(v.w);
    }
  }
  if (tid < 128) { s_fc1b[tid] = fc1b[tid]; s_fc2W[tid] = fc2W[tid]; }
  else if (tid < 160) s_rpW[tid - 128] = rpW[tid - 128];
  {
    const int l = tid >> 3, d0 = (tid & 7) * 8;
    const bf16* src = kvbuf + ((size_t)(b * kT + t0 + l) * (2 * kC)) + (size_t)s * kC + h * kHS + d0;
    short8 u = *reinterpret_cast<const short8*>(src);
    const float* wp = wpe + l * kHS + d0;
#pragma unroll
    for (int e = 0; e < 8; ++e) {
      const int d = d0 + e;
      XU[d * 40 + l] = u[e];
      const float xv = bu2f((unsigned short)u[e]) + wp[e];
      XPE[d * 40 + l] = fbits(xv);
    }
  }
  __syncthreads();

  const short8 af = *reinterpret_cast<const short8*>(&XPE[(w * 16 + fr) * 40 + q * 8]);
  f32x4 acc[8];
#pragma unroll
  for (int nt = 0; nt < 8; ++nt) {
    const short8 bf_ = *reinterpret_cast<const short8*>(&FC1[(nt * 16 + fr) * 40 + q * 8]);
    acc[nt] = __builtin_amdgcn_mfma_f32_16x16x32_bf16(af, bf_, (f32x4){0.f, 0.f, 0.f, 0.f}, 0, 0, 0);
  }

  float sum[4] = {0.f, 0.f, 0.f, 0.f};
#pragma unroll
  for (int nt = 0; nt < 8; ++nt) {
    const int j = nt * 16 + fr;
    const float bb = s_fc1b[j];
    const float w2 = s_fc2W[j];
#pragma unroll
    for (int r = 0; r < 4; ++r)
      sum[r] += gelu_fast(acc[nt][r] + bb) * w2;
  }
#pragma unroll
  for (int r = 0; r < 4; ++r) {
    const int d = w * 16 + q * 4 + r;
#pragma unroll
    for (int e = 0; e < 2; ++e) {
      const int l = fr * 2 + e;
      sum[r] += bu2f((unsigned short)XU[d * 40 + l]) * s_rpW[l];
    }
  }
#pragma unroll
  for (int off = 1; off <= 8; off <<= 1)
#pragma unroll
    for (int r = 0; r < 4; ++r) sum[r] += __shfl_xor(sum[r], off);

  if (fr == 0) {
    const float c0 = fc2b[0] + rpb[0];
    bf16* op = outp + ((size_t)(b * kNH + h) * kNB + blk) * kHS;
#pragma unroll
    for (int r = 0; r < 4; ++r) {
      float v = sum[r] + c0;
      v = fminf(3.0f, fmaxf(-3.0f, v));
      op[w * 16 + q * 4 + r] = f2b(v);
    }
  }
}

// ---------------- FUSED attention, QBLK=128 [R24-proven] ----------------
__global__ __launch_bounds__(512) void fused_attn_mfma(
    const bf16* __restrict__ qkv, const bf16* __restrict__ kcomp,
    const bf16* __restrict__ vcomp, const bf16* __restrict__ gate,
    bf16* __restrict__ ybuf0)
{
  __shared__ __align__(16) short Qs[128 * 64];
  __shared__ __align__(16) short Ks[64 * 64];
  __shared__ __align__(16) short VTs[64 * 64];
  __shared__ __align__(16) short Ps[128 * 64];
  const int tid = threadIdx.x;
  const int lane = tid & 63;
  const int w = tid >> 6;                 // 0..7; wave owns q rows [w*16, w*16+16)
  const int fr = lane & 15;
  const int g  = lane >> 4;
  const int h  = blockIdx.y;
  const int b  = blockIdx.z;
  const int t0 = blockIdx.x * 128;
  bf16* ybuf = ybuf0 + (size_t)b * kT * kC;
  const size_t rs = 3 * kC;
  const bf16* qbase = qkv + ((size_t)b * kT) * rs + h * kHS;
  const bf16* kbase = qbase + kC;
  const bf16* vbase = qbase + 2 * kC;
  const bf16* kb = kcomp + ((size_t)(b * kNH + h)) * kNB * kHS;
  const bf16* vb = vcomp + ((size_t)(b * kNH + h)) * kNB * kHS;

  // stage Q once (128 rows)
  for (int c = tid; c < 1024; c += 512) {
    const int r = c >> 3, p = c & 7;
    short8 v = *reinterpret_cast<const short8*>(qbase + (size_t)(t0 + r) * rs + p * 8);
    *reinterpret_cast<short8*>(&Qs[r * 64 + ((p ^ (r & 7)) << 3)]) = v;
  }
  __syncthreads();
  short8 qf[2];
  {
    const int r = w * 16 + fr;
#pragma unroll
    for (int dc = 0; dc < 2; ++dc) {
      const int d0 = dc * 32 + g * 8;
      qf[dc] = *reinterpret_cast<const short8*>(&Qs[r * 64 + (d0 ^ ((r & 7) << 3))]);
    }
  }
  const int qrow0 = t0 + w * 16 + g * 4;

  // ================= phase 1: local sliding-window attention =================
  f32x4 accL[4];
  float m[4], l[4];
#pragma unroll
  for (int r = 0; r < 4; ++r) { m[r] = -1e30f; l[r] = 0.f; }
#pragma unroll
  for (int dt = 0; dt < 4; ++dt) accL[dt] = (f32x4){0.f, 0.f, 0.f, 0.f};

  const int jb0 = (t0 >= 256) ? (t0 - 256) : 0;
  for (int jb = jb0; jb <= t0 + 64; jb += 64) {
    // fully-valid tiles for all 128 rows: jb in [t0-128, t0-64]
    const bool masked = !((jb >= t0 - 128) && (jb <= t0 - 64));
    __syncthreads();
    for (int c = tid; c < 512; c += 512) {
      const int r = c >> 3, p = c & 7;
      short8 v = *reinterpret_cast<const short8*>(kbase + (size_t)(jb + r) * rs + p * 8);
      *reinterpret_cast<short8*>(&Ks[r * 64 + ((p ^ (r & 7)) << 3)]) = v;
    }
    for (int c = tid; c < 512; c += 512) {
      const int r = c >> 3, p = c & 7;
      short8 v = *reinterpret_cast<const short8*>(vbase + (size_t)(jb + r) * rs + p * 8);
#pragma unroll
      for (int e = 0; e < 8; ++e) {
        const int d = p * 8 + e;
        VTs[d * 64 + (r ^ ((d & 7) << 3))] = v[e];
      }
    }
    __syncthreads();

    f32x4 S[4];
#pragma unroll
    for (int ks = 0; ks < 4; ++ks) S[ks] = (f32x4){0.f, 0.f, 0.f, 0.f};
#pragma unroll
    for (int ks = 0; ks < 4; ++ks) {
      const int kr = ks * 16 + fr;
#pragma unroll
      for (int dc = 0; dc < 2; ++dc) {
        const int d0 = dc * 32 + g * 8;
        short8 kf = *reinterpret_cast<const short8*>(&Ks[kr * 64 + (d0 ^ ((kr & 7) << 3))]);
        S[ks] = __builtin_amdgcn_mfma_f32_16x16x32_bf16(qf[dc], kf, S[ks], 0, 0, 0);
      }
    }

    float rowmax[4];
#pragma unroll
    for (int r = 0; r < 4; ++r) rowmax[r] = -1e30f;
#pragma unroll
    for (int ks = 0; ks < 4; ++ks) {
      const int j = jb + ks * 16 + fr;
#pragma unroll
      for (int r = 0; r < 4; ++r) {
        float s = S[ks][r] * 0.125f;
        if (masked) {
          const int i = qrow0 + r;
          if (!((j <= i) && (j > i - 256))) s = -1e30f;
        }
        S[ks][r] = s;
        rowmax[r] = fmaxf(rowmax[r], s);
      }
    }
#pragma unroll
    for (int off = 1; off <= 8; off <<= 1)
#pragma unroll
      for (int r = 0; r < 4; ++r)
        rowmax[r] = fmaxf(rowmax[r], __shfl_xor(rowmax[r], off));

    float resc[4], psum[4];
#pragma unroll
    for (int r = 0; r < 4; ++r) {
      const float mn = fmaxf(m[r], rowmax[r]);
      resc[r] = __expf(m[r] - mn);
      m[r] = mn;
      psum[r] = 0.f;
    }
#pragma unroll
    for (int ks = 0; ks < 4; ++ks) {
      const int j = jb + ks * 16 + fr;
#pragma unroll
      for (int r = 0; r < 4; ++r) {
        float p = __expf(S[ks][r] - m[r]);
        if (masked) {
          const int i = qrow0 + r;
          if (!((j <= i) && (j > i - 256))) p = 0.f;
        }
        S[ks][r] = p;
        psum[r] += p;
      }
    }
#pragma unroll
    for (int off = 1; off <= 8; off <<= 1)
#pragma unroll
      for (int r = 0; r < 4; ++r) psum[r] += __shfl_xor(psum[r], off);
#pragma unroll
    for (int r = 0; r < 4; ++r) l[r] = l[r] * resc[r] + psum[r];
#pragma unroll
    for (int dt = 0; dt < 4; ++dt)
#pragma unroll
      for (int r = 0; r < 4; ++r) accL[dt][r] *= resc[r];

#pragma unroll
    for (int ks = 0; ks < 4; ++ks)
#pragma unroll
      for (int r = 0; r < 4; ++r) {
        const int prow = w * 16 + g * 4 + r;
        const int pcol = ks * 16 + fr;
        Ps[prow * 64 + (pcol ^ ((prow & 7) << 3))] = fbits(S[ks][r]);
      }

#pragma unroll
    for (int kc = 0; kc < 2; ++kc) {
      const int prow = w * 16 + fr;
      const int k0 = kc * 32 + g * 8;
      short8 pf = *reinterpret_cast<const short8*>(&Ps[prow * 64 + (k0 ^ ((prow & 7) << 3))]);
#pragma unroll
      for (int dt = 0; dt < 4; ++dt) {
        const int dr = dt * 16 + fr;
        short8 vf = *reinterpret_cast<const short8*>(&VTs[dr * 64 + (k0 ^ ((dr & 7) << 3))]);
        accL[dt] = __builtin_amdgcn_mfma_f32_16x16x32_bf16(pf, vf, accL[dt], 0, 0, 0);
      }
    }
  }
  // finalize local: accL now holds yl
#pragma unroll
  for (int dt = 0; dt < 4; ++dt)
#pragma unroll
    for (int r = 0; r < 4; ++r) accL[dt][r] /= l[r];

  // ================= phase 2: compressed-block attention =================
  f32x4 accC[4];
#pragma unroll
  for (int r = 0; r < 4; ++r) { m[r] = -1e30f; l[r] = 0.f; }
#pragma unroll
  for (int dt = 0; dt < 4; ++dt) accC[dt] = (f32x4){0.f, 0.f, 0.f, 0.f};

  const int ntiles = ((t0 + 126) >> 10) + 1;   // 1 or 2 tiles of 64 key blocks
  for (int tb = 0; tb < ntiles; ++tb) {
    const int jb = tb * 64;
    const bool masked = !(((jb + 63) < kNB) && ((jb + 63) * kST < t0));
    __syncthreads();
    for (int c = tid; c < 512; c += 512) {
      const int r = c >> 3, p = c & 7;
      const int rr = (jb + r < kNB) ? (jb + r) : (kNB - 1);
      short8 v = *reinterpret_cast<const short8*>(kb + (size_t)rr * kHS + p * 8);
      *reinterpret_cast<short8*>(&Ks[r * 64 + ((p ^ (r & 7)) << 3)]) = v;
    }
    for (int c = tid; c < 512; c += 512) {
      const int r = c >> 3, p = c & 7;
      const int rr = (jb + r < kNB) ? (jb + r) : (kNB - 1);
      short8 v = *reinterpret_cast<const short8*>(vb + (size_t)rr * kHS + p * 8);
#pragma unroll
      for (int e = 0; e < 8; ++e) {
        const int d = p * 8 + e;
        VTs[d * 64 + (r ^ ((d & 7) << 3))] = v[e];
      }
    }
    __syncthreads();

    f32x4 S[4];
#pragma unroll
    for (int ks = 0; ks < 4; ++ks) S[ks] = (f32x4){0.f, 0.f, 0.f, 0.f};
#pragma unroll
    for (int ks = 0; ks < 4; ++ks) {
      const int kr = ks * 16 + fr;
#pragma unroll
      for (int dc = 0; dc < 2; ++dc) {
        const int d0 = dc * 32 + g * 8;
        short8 kf = *reinterpret_cast<const short8*>(&Ks[kr * 64 + (d0 ^ ((kr & 7) << 3))]);
        S[ks] = __builtin_amdgcn_mfma_f32_16x16x32_bf16(qf[dc], kf, S[ks], 0, 0, 0);
      }
    }

    float rowmax[4];
#pragma unroll
    for (int r = 0; r < 4; ++r) rowmax[r] = -1e30f;
#pragma unroll
    for (int ks = 0; ks < 4; ++ks) {
      const int n = jb + ks * 16 + fr;
#pragma unroll
      for (int r = 0; r < 4; ++r) {
        float s = S[ks][r] * 0.125f;
        if (masked) {
          const int i = qrow0 + r;
          if (!((n < kNB) && (n * kST < i))) s = -1e30f;
        }
        S[ks][r] = s;
        rowmax[r] = fmaxf(rowmax[r], s);
      }
    }
#pragma unroll
    for (int off = 1; off <= 8; off <<= 1)
#pragma unroll
      for (int r = 0; r < 4; ++r)
        rowmax[r] = fmaxf(rowmax[r], __shfl_xor(rowmax[r], off));

    float resc[4], psum[4];
#pragma unroll
    for (int r = 0; r < 4; ++r) {
      const float mn = fmaxf(m[r], rowmax[r]);
      resc[r] = __expf(m[r] - mn);
      m[r] = mn;
      psum[r] = 0.f;
    }
#pragma unroll
    for (int ks = 0; ks < 4; ++ks) {
      const int n = jb + ks * 16 + fr;
#pragma unroll
      for (int r = 0; r < 4; ++r) {
        float p = __expf(S[ks][r] - m[r]);
        if (masked) {
          const int i = qrow0 + r;
          if (!((n < kNB) && (n * kST < i))) p = 0.f;
        }
        S[ks][r] = p;
        psum[r] += p;
      }
    }
#pragma unroll
    for (int off = 1; off <= 8; off <<= 1)
#pragma unroll
      for (int r = 0; r < 4; ++r) psum[r] += __shfl_xor(psum[r], off);
#pragma unroll
    for (int r = 0; r < 4; ++r) l[r] = l[r] * resc[r] + psum[r];
#pragma unroll
    for (int dt = 0; dt < 4; ++dt)
#pragma unroll
      for (int r = 0; r < 4; ++r) accC[dt][r] *= resc[r];

#pragma unroll
    for (int ks = 0; ks < 4; ++ks)
#pragma unroll
      for (int r = 0; r < 4; ++r) {
        const int prow = w * 16 + g * 4 + r;
        const int pcol = ks * 16 + fr;
        Ps[prow * 64 + (pcol ^ ((prow & 7) << 3))] = fbits(S[ks][r]);
      }

#pragma unroll
    for (int kc = 0; kc < 2; ++kc) {
      const int prow = w * 16 + fr;
      const int k0 = kc * 32 + g * 8;
      short8 pf = *reinterpret_cast<const short8*>(&Ps[prow * 64 + (k0 ^ ((prow & 7) << 3))]);
#pragma unroll
      for (int dt = 0; dt < 4; ++dt) {
        const int dr = dt * 16 + fr;
        short8 vf = *reinterpret_cast<const short8*>(&VTs[dr * 64 + (k0 ^ ((dr & 7) << 3))]);
        accC[dt] = __builtin_amdgcn_mfma_f32_16x16x32_bf16(pf, vf, accC[dt], 0, 0, 0);
      }
    }
  }

  // ================= phase 3: gate mix + single write =================
#pragma unroll
  for (int r = 0; r < 4; ++r) {
    const int i = t0 + w * 16 + g * 4 + r;
    const float inv = (l[r] > 0.f) ? (1.f / l[r]) : 0.f;
#pragma unroll
    for (int dt = 0; dt < 4; ++dt) {
      const int d = dt * 16 + fr;
      const float yc = accC[dt][r] * inv;
      const float gg = b2f(gate[((size_t)(b * kT + i)) * kC + h * kHS + d]);
      ybuf[(size_t)i * kC + h * kHS + d] = f2b(gg * accL[dt][r] + (1.f - gg) * yc);
    }
  }
}

extern "C" void kernel_launch(void* const* d_in, const int* in_sizes, int n_in,
                              void* d_out, int out_size, void* d_ws, size_t ws_size,
                              hipStream_t stream)
{
  (void)in_sizes; (void)n_in; (void)out_size; (void)ws_size; (void)kM; (void)kWIN;
  const float* x      = (const float*)d_in[0];
  const float* Wqkv   = (const float*)d_in[1];
  const float* bqkv   = (const float*)d_in[2];
  const float* Wcomp  = (const float*)d_in[3];
  const float* bcomp  = (const float*)d_in[4];
  const float* Wproj  = (const float*)d_in[5];
  const float* bproj  = (const float*)d_in[6];
  const float* k_fc1W = (const float*)d_in[7];
  const float* k_fc1b = (const float*)d_in[8];
  const float* k_fc2W = (const float*)d_in[9];
  const float* k_fc2b = (const float*)d_in[10];
  const float* k_rpW  = (const float*)d_in[11];
  const float* k_rpb  = (const float*)d_in[12];
  const float* k_wpe  = (const float*)d_in[13];
  const float* v_fc1W = (const float*)d_in[14];
  const float* v_fc1b = (const float*)d_in[15];
  const float* v_fc2W = (const float*)d_in[16];
  const float* v_fc2b = (const float*)d_in[17];
  const float* v_rpW  = (const float*)d_in[18];
  const float* v_rpb  = (const float*)d_in[19];
  const float* v_wpe  = (const float*)d_in[20];
  const float* Wg1    = (const float*)d_in[21];
  const float* bg1    = (const float*)d_in[22];
  const float* Wg2    = (const float*)d_in[23];
  const float* bg2    = (const float*)d_in[24];

  // ---- Workspace (peak 51,372,032 B, identical to proven footprint) ----
  char* wsb = (char*)d_ws;
  bf16* xbf   = (bf16*)(wsb + 0);
  bf16* wscr  = (bf16*)(wsb + 8388608);
  bf16* big   = (bf16*)(wsb + 16777216);
  bf16* ybuf  = (bf16*)(wsb + 41943040);
  bf16* kcomp = (bf16*)(wsb + 50331648);
  bf16* vcomp = (bf16*)(wsb + 50851840);
  bf16* gate  = (bf16*)((char*)d_out + 8388608);
  float* out  = (float*)d_out;

  const int cg = 2048;
  f32_to_bf16<<<cg, 256, 0, stream>>>(x, xbf, 1048576);
  f32_to_bf16<<<cg, 256, 0, stream>>>(Wg1, wscr, 1048576);
  gemm_bf16<1, bf16><<<1024, 512, 0, stream>>>(xbf, wscr, bg1, big, 4096, 4096, 1024, 32);
  f32_to_bf16<<<cg, 256, 0, stream>>>(Wg2, wscr, 1048576);
  gemm_bf16_t64<3, bf16><<<1024, 256, 0, stream>>>(big, wscr, bg2, gate, 4096, 1024, 4096, 16);
  f32_to_bf16<<<cg, 256, 0, stream>>>(Wcomp, wscr, 524288);
  gemm_bf16<0, bf16><<<512, 512, 0, stream>>>(xbf, wscr, bcomp, big, 4096, 2048, 1024, 16);
  comp_mlp_mfma<<<dim3(kNB, kNH, kB * 2), 256, 0, stream>>>(
      big,
      k_fc1W, k_fc1b, k_fc2W, k_fc2b, k_rpW, k_rpb, k_wpe, kcomp,
      v_fc1W, v_fc1b, v_fc2W, v_fc2b, v_rpW, v_rpb, v_wpe, vcomp);
  f32_to_bf16<<<cg, 256, 0, stream>>>(Wqkv, wscr, 786432);
  gemm_bf16<0, bf16><<<768, 512, 0, stream>>>(xbf, wscr, bqkv, big, 4096, 3072, 1024, 24);
  f32_to_bf16<<<cg, 256, 0, stream>>>(Wproj, wscr, 262144);
  // fused attention (local + compressed + gate mix), QBLK=128, both batches
  fused_attn_mfma<<<dim3(kT / 128, kNH, kB), 512, 0, stream>>>(big, kcomp, vcomp, gate, ybuf);
  // single merged projection over both batches (overwrites gate region after use)
  gemm_bf16_t64<0, float><<<1024, 256, 0, stream>>>(ybuf, wscr, bproj, out, 4096, 1024, 1024, 16);
}

// Round 26
// 278.434 us; speedup vs baseline: 1.0128x; 1.0128x over previous
//
#include <hip/hip_runtime.h>
#include <hip/hip_bf16.h>

typedef __hip_bfloat16 bf16;

constexpr int kB = 2, kT = 2048, kC = 1024, kNH = 16, kHS = 64;
constexpr int kL = 32, kST = 16, kWIN = 256;
constexpr int kNB = (kT - kL) / kST + 1;   // 127
constexpr int kM = kB * kT;                // 4096

typedef __attribute__((ext_vector_type(8))) short short8;   // bf16 MFMA A/B frag (4 VGPRs)
typedef __attribute__((ext_vector_type(4))) short short4v;
typedef __attribute__((ext_vector_type(4))) float f32x4;

__device__ __forceinline__ float b2f(bf16 v) { return __bfloat162float(v); }
__device__ __forceinline__ bf16  f2b(float v) { return __float2bfloat16(v); }
__device__ __forceinline__ float bu2f(unsigned int u) { return __uint_as_float(u << 16); }
__device__ __forceinline__ float gelu_f(float v) { return 0.5f * v * (1.0f + erff(v * 0.70710678118654752f)); }
// branchless tanh-form GELU (max |err| vs exact ~3e-4); used only in comp_mlp
__device__ __forceinline__ float gelu_fast(float v) {
  const float w = v * (1.5957691216f + 0.0713548162f * v * v);   // 2*sqrt(2/pi)*(v+0.044715v^3)
  return v * __builtin_amdgcn_rcpf(1.0f + __expf(-w));           // v * sigmoid(w)
}
__device__ __forceinline__ short fbits(float v) {
  return (short)__builtin_bit_cast(unsigned short, f2b(v));
}
// async global->LDS, 16 bytes per lane (dest = wave-uniform base + lane*16)
__device__ __forceinline__ void gl16(const bf16* g, bf16* l) {
  __builtin_amdgcn_global_load_lds(
      (const __attribute__((address_space(1))) void*)g,
      (__attribute__((address_space(3))) void*)l, 16, 0, 0);
}

// ---------------- fp32 -> bf16 conversion (vectorized, grid-stride) ----------------
__global__ __launch_bounds__(256) void f32_to_bf16(const float* __restrict__ src,
                                                   bf16* __restrict__ dst, int n4) {
  int i = blockIdx.x * 256 + threadIdx.x;
  const int stride = gridDim.x * 256;
  for (; i < n4; i += stride) {
    float4 v = ((const float4*)src)[i];
    short4v w; w.x = fbits(v.x); w.y = fbits(v.y); w.z = fbits(v.z); w.w = fbits(v.w);
    ((short4v*)dst)[i] = w;
  }
}

// ---------------- all-bf16 MFMA GEMM: 128x128 tile, BK=64, 8 waves (2x4) [R23-proven] ----------------
template<int EPI, typename TY>
__global__ __launch_bounds__(512) void gemm_bf16(
    const bf16* __restrict__ X, const bf16* __restrict__ W,
    const float* __restrict__ bias, TY* __restrict__ Y,
    int M, int N, int K, int nbx)
{
  __shared__ __align__(16) bf16 As[128 * 64];
  __shared__ __align__(16) bf16 Bs[128 * 64];
  const int nwg = gridDim.x;
  const int bid = blockIdx.x;
  const int swz = (bid & 7) * (nwg >> 3) + (bid >> 3);
  const int bm = (swz / nbx) * 128;
  const int bn = (swz % nbx) * 128;
  const int tid = threadIdx.x;
  const int lane = tid & 63;
  const int w = tid >> 6;
  const int wr = w >> 2, wc = w & 3;      // 2x4 wave grid; wave tile 64 x 32
  const int fr = lane & 15, q = lane >> 4;
  const int srow = lane >> 3;
  const int scol = (lane & 7) * 8;

  f32x4 acc[4][2];
#pragma unroll
  for (int i = 0; i < 4; ++i)
#pragma unroll
    for (int j = 0; j < 2; ++j) acc[i][j] = (f32x4){0.f, 0.f, 0.f, 0.f};

  const bf16* Xb = X + (size_t)bm * K;
  const bf16* Wb = W + (size_t)bn * K;

  for (int k0 = 0; k0 < K; k0 += 64) {
    __syncthreads();
#pragma unroll
    for (int i = 0; i < 2; ++i) {
      const int r = w * 16 + i * 8 + srow;
      const int sc = scol ^ ((r & 7) << 3);   // pre-swizzled global source chunk
      gl16(Xb + (size_t)r * K + k0 + sc, &As[r * 64 + scol]);
      gl16(Wb + (size_t)r * K + k0 + sc, &Bs[r * 64 + scol]);
    }
    __syncthreads();
#pragma unroll
    for (int kk = 0; kk < 2; ++kk) {
      short8 af[4], bfr[2];
#pragma unroll
      for (int i = 0; i < 4; ++i) {
        const int ar = wr * 64 + i * 16 + fr;
        af[i] = *reinterpret_cast<const short8*>(&As[ar * 64 + ((kk * 32 + q * 8) ^ ((ar & 7) << 3))]);
      }
#pragma unroll
      for (int j = 0; j < 2; ++j) {
        const int br = wc * 32 + j * 16 + fr;
        bfr[j] = *reinterpret_cast<const short8*>(&Bs[br * 64 + ((kk * 32 + q * 8) ^ ((br & 7) << 3))]);
      }
#pragma unroll
      for (int i = 0; i < 4; ++i)
#pragma unroll
        for (int j = 0; j < 2; ++j)
          acc[i][j] = __builtin_amdgcn_mfma_f32_16x16x32_bf16(af[i], bfr[j], acc[i][j], 0, 0, 0);
    }
  }

#pragma unroll
  for (int j = 0; j < 2; ++j) {
    const int gcol = bn + wc * 32 + j * 16 + fr;
    const float bv = bias[gcol];
#pragma unroll
    for (int i = 0; i < 4; ++i) {
      const int grow0 = bm + wr * 64 + i * 16 + q * 4;
#pragma unroll
      for (int r = 0; r < 4; ++r) {
        float v = acc[i][j][r] + bv;
        if (EPI == 1) v = gelu_f(v);
        if (EPI == 3) v = 1.f / (1.f + expf(-v));
        if constexpr (sizeof(TY) == 2) Y[(size_t)(grow0 + r) * N + gcol] = f2b(v);
        else                           ((float*)Y)[(size_t)(grow0 + r) * N + gcol] = v;
      }
    }
  }
}

// ---------------- small-tile GEMM: 64x64 tile, BK=64, 4 waves (2x2) [R24-proven] ----------------
template<int EPI, typename TY>
__global__ __launch_bounds__(256) void gemm_bf16_t64(
    const bf16* __restrict__ X, const bf16* __restrict__ W,
    const float* __restrict__ bias, TY* __restrict__ Y,
    int M, int N, int K, int nbx)
{
  __shared__ __align__(16) bf16 As[64 * 64];
  __shared__ __align__(16) bf16 Bs[64 * 64];
  const int nwg = gridDim.x;
  const int bid = blockIdx.x;
  const int swz = (bid & 7) * (nwg >> 3) + (bid >> 3);
  const int bm = (swz / nbx) * 64;
  const int bn = (swz % nbx) * 64;
  const int tid = threadIdx.x;
  const int lane = tid & 63;
  const int w = tid >> 6;                 // 0..3
  const int wr = w >> 1, wc = w & 1;      // 2x2 wave grid; wave tile 32 x 32
  const int fr = lane & 15, q = lane >> 4;
  const int srow = lane >> 3;
  const int scol = (lane & 7) * 8;

  f32x4 acc[2][2];
#pragma unroll
  for (int i = 0; i < 2; ++i)
#pragma unroll
    for (int j = 0; j < 2; ++j) acc[i][j] = (f32x4){0.f, 0.f, 0.f, 0.f};

  const bf16* Xb = X + (size_t)bm * K;
  const bf16* Wb = W + (size_t)bn * K;

  for (int k0 = 0; k0 < K; k0 += 64) {
    __syncthreads();
#pragma unroll
    for (int i = 0; i < 2; ++i) {        // wave w stages rows [w*16, w*16+16) of A and B
      const int r = w * 16 + i * 8 + srow;
      const int sc = scol ^ ((r & 7) << 3);
      gl16(Xb + (size_t)r * K + k0 + sc, &As[r * 64 + scol]);
      gl16(Wb + (size_t)r * K + k0 + sc, &Bs[r * 64 + scol]);
    }
    __syncthreads();
#pragma unroll
    for (int kk = 0; kk < 2; ++kk) {
      short8 af[2], bfr[2];
#pragma unroll
      for (int i = 0; i < 2; ++i) {
        const int ar = wr * 32 + i * 16 + fr;
        af[i] = *reinterpret_cast<const short8*>(&As[ar * 64 + ((kk * 32 + q * 8) ^ ((ar & 7) << 3))]);
      }
#pragma unroll
      for (int j = 0; j < 2; ++j) {
        const int br = wc * 32 + j * 16 + fr;
        bfr[j] = *reinterpret_cast<const short8*>(&Bs[br * 64 + ((kk * 32 + q * 8) ^ ((br & 7) << 3))]);
      }
#pragma unroll
      for (int i = 0; i < 2; ++i)
#pragma unroll
        for (int j = 0; j < 2; ++j)
          acc[i][j] = __builtin_amdgcn_mfma_f32_16x16x32_bf16(af[i], bfr[j], acc[i][j], 0, 0, 0);
    }
  }

#pragma unroll
  for (int j = 0; j < 2; ++j) {
    const int gcol = bn + wc * 32 + j * 16 + fr;
    const float bv = bias[gcol];
#pragma unroll
    for (int i = 0; i < 2; ++i) {
      const int grow0 = bm + wr * 32 + i * 16 + q * 4;
#pragma unroll
      for (int r = 0; r < 4; ++r) {
        float v = acc[i][j][r] + bv;
        if (EPI == 1) v = gelu_f(v);
        if (EPI == 3) v = 1.f / (1.f + expf(-v));
        if constexpr (sizeof(TY) == 2) Y[(size_t)(grow0 + r) * N + gcol] = f2b(v);
        else                           ((float*)Y)[(size_t)(grow0 + r) * N + gcol] = v;
      }
    }
  }
}

// ---------------- Compression MLP via MFMA (R22-proven: gelu_fast) ----------------
__global__ __launch_bounds__(256) void comp_mlp_mfma(
    const bf16* __restrict__ kvbuf,
    const float* __restrict__ k_fc1W, const float* __restrict__ k_fc1b,
    const float* __restrict__ k_fc2W, const float* __restrict__ k_fc2b,
    const float* __restrict__ k_rpW,  const float* __restrict__ k_rpb,
    const float* __restrict__ k_wpe,  bf16* __restrict__ k_out,
    const float* __restrict__ v_fc1W, const float* __restrict__ v_fc1b,
    const float* __restrict__ v_fc2W, const float* __restrict__ v_fc2b,
    const float* __restrict__ v_rpW,  const float* __restrict__ v_rpb,
    const float* __restrict__ v_wpe,  bf16* __restrict__ v_out)
{
  __shared__ __align__(16) short XPE[64 * 40];
  __shared__ __align__(16) short XU [64 * 40];
  __shared__ __align__(16) short FC1[128 * 40];
  __shared__ float s_fc1b[128];
  __shared__ float s_fc2W[128];
  __shared__ float s_rpW[32];
  const int tid = threadIdx.x;
  const int lane = tid & 63;
  const int w = tid >> 6;
  const int fr = lane & 15, q = lane >> 4;
  const int blk = blockIdx.x;
  const int h = blockIdx.y;
  const int s = blockIdx.z & 1;
  const int b = blockIdx.z >> 1;
  const int t0 = blk * kST;
  const float* fc1W = s ? v_fc1W : k_fc1W;
  const float* fc1b = s ? v_fc1b : k_fc1b;
  const float* fc2W = s ? v_fc2W : k_fc2W;
  const float* fc2b = s ? v_fc2b : k_fc2b;
  const float* rpW  = s ? v_rpW  : k_rpW;
  const float* rpb  = s ? v_rpb  : k_rpb;
  const float* wpe  = s ? v_wpe  : k_wpe;
  bf16* outp        = s ? v_out  : k_out;

  {
    const int base = tid * 16;
#pragma unroll
    for (int c = 0; c < 4; ++c) {
      float4 v = *reinterpret_cast<const float4*>(fc1W + base + c * 4);
      const int idx = base + c * 4;
      short* dst = &FC1[(idx >> 5) * 40 + (idx & 31)];
      dst[0] = fbits(v.x); dst[1] = fbits(v.y); dst[2] = fbits(v.z); dst[3] = fbits(v.w);
    }
  }
  if (tid < 128) { s_fc1b[tid] = fc1b[tid]; s_fc2W[tid] = fc2W[tid]; }
  else if (tid < 160) s_rpW[tid - 128] = rpW[tid - 128];
  {
    const int l = tid >> 3, d0 = (tid & 7) * 8;
    const bf16* src = kvbuf + ((size_t)(b * kT + t0 + l) * (2 * kC)) + (size_t)s * kC + h * kHS + d0;
    short8 u = *reinterpret_cast<const short8*>(src);
    const float* wp = wpe + l * kHS + d0;
#pragma unroll
    for (int e = 0; e < 8; ++e) {
      const int d = d0 + e;
      XU[d * 40 + l] = u[e];
      const float xv = bu2f((unsigned short)u[e]) + wp[e];
      XPE[d * 40 + l] = fbits(xv);
    }
  }
  __syncthreads();

  const short8 af = *reinterpret_cast<const short8*>(&XPE[(w * 16 + fr) * 40 + q * 8]);
  f32x4 acc[8];
#pragma unroll
  for (int nt = 0; nt < 8; ++nt) {
    const short8 bf_ = *reinterpret_cast<const short8*>(&FC1[(nt * 16 + fr) * 40 + q * 8]);
    acc[nt] = __builtin_amdgcn_mfma_f32_16x16x32_bf16(af, bf_, (f32x4){0.f, 0.f, 0.f, 0.f}, 0, 0, 0);
  }

  float sum[4] = {0.f, 0.f, 0.f, 0.f};
#pragma unroll
  for (int nt = 0; nt < 8; ++nt) {
    const int j = nt * 16 + fr;
    const float bb = s_fc1b[j];
    const float w2 = s_fc2W[j];
#pragma unroll
    for (int r = 0; r < 4; ++r)
      sum[r] += gelu_fast(acc[nt][r] + bb) * w2;
  }
#pragma unroll
  for (int r = 0; r < 4; ++r) {
    const int d = w * 16 + q * 4 + r;
#pragma unroll
    for (int e = 0; e < 2; ++e) {
      const int l = fr * 2 + e;
      sum[r] += bu2f((unsigned short)XU[d * 40 + l]) * s_rpW[l];
    }
  }
#pragma unroll
  for (int off = 1; off <= 8; off <<= 1)
#pragma unroll
    for (int r = 0; r < 4; ++r) sum[r] += __shfl_xor(sum[r], off);

  if (fr == 0) {
    const float c0 = fc2b[0] + rpb[0];
    bf16* op = outp + ((size_t)(b * kNH + h) * kNB + blk) * kHS;
#pragma unroll
    for (int r = 0; r < 4; ++r) {
      float v = sum[r] + c0;
      v = fminf(3.0f, fmaxf(-3.0f, v));
      op[w * 16 + q * 4 + r] = f2b(v);
    }
  }
}

// ---------------- FUSED attention, QBLK=128 [R24-proven] ----------------
__global__ __launch_bounds__(512) void fused_attn_mfma(
    const bf16* __restrict__ qkv, const bf16* __restrict__ kcomp,
    const bf16* __restrict__ vcomp, const bf16* __restrict__ gate,
    bf16* __restrict__ ybuf0)
{
  __shared__ __align__(16) short Qs[128 * 64];
  __shared__ __align__(16) short Ks[64 * 64];
  __shared__ __align__(16) short VTs[64 * 64];
  __shared__ __align__(16) short Ps[128 * 64];
  const int tid = threadIdx.x;
  const int lane = tid & 63;
  const int w = tid >> 6;                 // 0..7; wave owns q rows [w*16, w*16+16)
  const int fr = lane & 15;
  const int g  = lane >> 4;
  const int h  = blockIdx.y;
  const int b  = blockIdx.z;
  const int t0 = blockIdx.x * 128;
  bf16* ybuf = ybuf0 + (size_t)b * kT * kC;
  const size_t rs = 3 * kC;
  const bf16* qbase = qkv + ((size_t)b * kT) * rs + h * kHS;
  const bf16* kbase = qbase + kC;
  const bf16* vbase = qbase + 2 * kC;
  const bf16* kb = kcomp + ((size_t)(b * kNH + h)) * kNB * kHS;
  const bf16* vb = vcomp + ((size_t)(b * kNH + h)) * kNB * kHS;

  // stage Q once (128 rows)
  for (int c = tid; c < 1024; c += 512) {
    const int r = c >> 3, p = c & 7;
    short8 v = *reinterpret_cast<const short8*>(qbase + (size_t)(t0 + r) * rs + p * 8);
    *reinterpret_cast<short8*>(&Qs[r * 64 + ((p ^ (r & 7)) << 3)]) = v;
  }
  __syncthreads();
  short8 qf[2];
  {
    const int r = w * 16 + fr;
#pragma unroll
    for (int dc = 0; dc < 2; ++dc) {
      const int d0 = dc * 32 + g * 8;
      qf[dc] = *reinterpret_cast<const short8*>(&Qs[r * 64 + (d0 ^ ((r & 7) << 3))]);
    }
  }
  const int qrow0 = t0 + w * 16 + g * 4;

  // ================= phase 1: local sliding-window attention =================
  f32x4 accL[4];
  float m[4], l[4];
#pragma unroll
  for (int r = 0; r < 4; ++r) { m[r] = -1e30f; l[r] = 0.f; }
#pragma unroll
  for (int dt = 0; dt < 4; ++dt) accL[dt] = (f32x4){0.f, 0.f, 0.f, 0.f};

  const int jb0 = (t0 >= 256) ? (t0 - 256) : 0;
  for (int jb = jb0; jb <= t0 + 64; jb += 64) {
    // fully-valid tiles for all 128 rows: jb in [t0-128, t0-64]
    const bool masked = !((jb >= t0 - 128) && (jb <= t0 - 64));
    __syncthreads();
    for (int c = tid; c < 512; c += 512) {
      const int r = c >> 3, p = c & 7;
      short8 v = *reinterpret_cast<const short8*>(kbase + (size_t)(jb + r) * rs + p * 8);
      *reinterpret_cast<short8*>(&Ks[r * 64 + ((p ^ (r & 7)) << 3)]) = v;
    }
    for (int c = tid; c < 512; c += 512) {
      const int r = c >> 3, p = c & 7;
      short8 v = *reinterpret_cast<const short8*>(vbase + (size_t)(jb + r) * rs + p * 8);
#pragma unroll
      for (int e = 0; e < 8; ++e) {
        const int d = p * 8 + e;
        VTs[d * 64 + (r ^ ((d & 7) << 3))] = v[e];
      }
    }
    __syncthreads();

    f32x4 S[4];
#pragma unroll
    for (int ks = 0; ks < 4; ++ks) S[ks] = (f32x4){0.f, 0.f, 0.f, 0.f};
#pragma unroll
    for (int ks = 0; ks < 4; ++ks) {
      const int kr = ks * 16 + fr;
#pragma unroll
      for (int dc = 0; dc < 2; ++dc) {
        const int d0 = dc * 32 + g * 8;
        short8 kf = *reinterpret_cast<const short8*>(&Ks[kr * 64 + (d0 ^ ((kr & 7) << 3))]);
        S[ks] = __builtin_amdgcn_mfma_f32_16x16x32_bf16(qf[dc], kf, S[ks], 0, 0, 0);
      }
    }

    float rowmax[4];
#pragma unroll
    for (int r = 0; r < 4; ++r) rowmax[r] = -1e30f;
#pragma unroll
    for (int ks = 0; ks < 4; ++ks) {
      const int j = jb + ks * 16 + fr;
#pragma unroll
      for (int r = 0; r < 4; ++r) {
        float s = S[ks][r] * 0.125f;
        if (masked) {
          const int i = qrow0 + r;
          if (!((j <= i) && (j > i - 256))) s = -1e30f;
        }
        S[ks][r] = s;
        rowmax[r] = fmaxf(rowmax[r], s);
      }
    }
#pragma unroll
    for (int off = 1; off <= 8; off <<= 1)
#pragma unroll
      for (int r = 0; r < 4; ++r)
        rowmax[r] = fmaxf(rowmax[r], __shfl_xor(rowmax[r], off));

    float resc[4], psum[4];
#pragma unroll
    for (int r = 0; r < 4; ++r) {
      const float mn = fmaxf(m[r], rowmax[r]);
      resc[r] = __expf(m[r] - mn);
      m[r] = mn;
      psum[r] = 0.f;
    }
#pragma unroll
    for (int ks = 0; ks < 4; ++ks) {
      const int j = jb + ks * 16 + fr;
#pragma unroll
      for (int r = 0; r < 4; ++r) {
        float p = __expf(S[ks][r] - m[r]);
        if (masked) {
          const int i = qrow0 + r;
          if (!((j <= i) && (j > i - 256))) p = 0.f;
        }
        S[ks][r] = p;
        psum[r] += p;
      }
    }
#pragma unroll
    for (int off = 1; off <= 8; off <<= 1)
#pragma unroll
      for (int r = 0; r < 4; ++r) psum[r] += __shfl_xor(psum[r], off);
#pragma unroll
    for (int r = 0; r < 4; ++r) l[r] = l[r] * resc[r] + psum[r];
#pragma unroll
    for (int dt = 0; dt < 4; ++dt)
#pragma unroll
      for (int r = 0; r < 4; ++r) accL[dt][r] *= resc[r];

#pragma unroll
    for (int ks = 0; ks < 4; ++ks)
#pragma unroll
      for (int r = 0; r < 4; ++r) {
        const int prow = w * 16 + g * 4 + r;
        const int pcol = ks * 16 + fr;
        Ps[prow * 64 + (pcol ^ ((prow & 7) << 3))] = fbits(S[ks][r]);
      }

#pragma unroll
    for (int kc = 0; kc < 2; ++kc) {
      const int prow = w * 16 + fr;
      const int k0 = kc * 32 + g * 8;
      short8 pf = *reinterpret_cast<const short8*>(&Ps[prow * 64 + (k0 ^ ((prow & 7) << 3))]);
#pragma unroll
      for (int dt = 0; dt < 4; ++dt) {
        const int dr = dt * 16 + fr;
        short8 vf = *reinterpret_cast<const short8*>(&VTs[dr * 64 + (k0 ^ ((dr & 7) << 3))]);
        accL[dt] = __builtin_amdgcn_mfma_f32_16x16x32_bf16(pf, vf, accL[dt], 0, 0, 0);
      }
    }
  }
  // finalize local: accL now holds yl
#pragma unroll
  for (int dt = 0; dt < 4; ++dt)
#pragma unroll
    for (int r = 0; r < 4; ++r) accL[dt][r] /= l[r];

  // ================= phase 2: compressed-block attention =================
  f32x4 accC[4];
#pragma unroll
  for (int r = 0; r < 4; ++r) { m[r] = -1e30f; l[r] = 0.f; }
#pragma unroll
  for (int dt = 0; dt < 4; ++dt) accC[dt] = (f32x4){0.f, 0.f, 0.f, 0.f};

  const int ntiles = ((t0 + 126) >> 10) + 1;   // 1 or 2 tiles of 64 key blocks
  for (int tb = 0; tb < ntiles; ++tb) {
    const int jb = tb * 64;
    const bool masked = !(((jb + 63) < kNB) && ((jb + 63) * kST < t0));
    __syncthreads();
    for (int c = tid; c < 512; c += 512) {
      const int r = c >> 3, p = c & 7;
      const int rr = (jb + r < kNB) ? (jb + r) : (kNB - 1);
      short8 v = *reinterpret_cast<const short8*>(kb + (size_t)rr * kHS + p * 8);
      *reinterpret_cast<short8*>(&Ks[r * 64 + ((p ^ (r & 7)) << 3)]) = v;
    }
    for (int c = tid; c < 512; c += 512) {
      const int r = c >> 3, p = c & 7;
      const int rr = (jb + r < kNB) ? (jb + r) : (kNB - 1);
      short8 v = *reinterpret_cast<const short8*>(vb + (size_t)rr * kHS + p * 8);
#pragma unroll
      for (int e = 0; e < 8; ++e) {
        const int d = p * 8 + e;
        VTs[d * 64 + (r ^ ((d & 7) << 3))] = v[e];
      }
    }
    __syncthreads();

    f32x4 S[4];
#pragma unroll
    for (int ks = 0; ks < 4; ++ks) S[ks] = (f32x4){0.f, 0.f, 0.f, 0.f};
#pragma unroll
    for (int ks = 0; ks < 4; ++ks) {
      const int kr = ks * 16 + fr;
#pragma unroll
      for (int dc = 0; dc < 2; ++dc) {
        const int d0 = dc * 32 + g * 8;
        short8 kf = *reinterpret_cast<const short8*>(&Ks[kr * 64 + (d0 ^ ((kr & 7) << 3))]);
        S[ks] = __builtin_amdgcn_mfma_f32_16x16x32_bf16(qf[dc], kf, S[ks], 0, 0, 0);
      }
    }

    float rowmax[4];
#pragma unroll
    for (int r = 0; r < 4; ++r) rowmax[r] = -1e30f;
#pragma unroll
    for (int ks = 0; ks < 4; ++ks) {
      const int n = jb + ks * 16 + fr;
#pragma unroll
      for (int r = 0; r < 4; ++r) {
        float s = S[ks][r] * 0.125f;
        if (masked) {
          const int i = qrow0 + r;
          if (!((n < kNB) && (n * kST < i))) s = -1e30f;
        }
        S[ks][r] = s;
        rowmax[r] = fmaxf(rowmax[r], s);
      }
    }
#pragma unroll
    for (int off = 1; off <= 8; off <<= 1)
#pragma unroll
      for (int r = 0; r < 4; ++r)
        rowmax[r] = fmaxf(rowmax[r], __shfl_xor(rowmax[r], off));

    float resc[4], psum[4];
#pragma unroll
    for (int r = 0; r < 4; ++r) {
      const float mn = fmaxf(m[r], rowmax[r]);
      resc[r] = __expf(m[r] - mn);
      m[r] = mn;
      psum[r] = 0.f;
    }
#pragma unroll
    for (int ks = 0; ks < 4; ++ks) {
      const int n = jb + ks * 16 + fr;
#pragma unroll
      for (int r = 0; r < 4; ++r) {
        float p = __expf(S[ks][r] - m[r]);
        if (masked) {
          const int i = qrow0 + r;
          if (!((n < kNB) && (n * kST < i))) p = 0.f;
        }
        S[ks][r] = p;
        psum[r] += p;
      }
    }
#pragma unroll
    for (int off = 1; off <= 8; off <<= 1)
#pragma unroll
      for (int r = 0; r < 4; ++r) psum[r] += __shfl_xor(psum[r], off);
#pragma unroll
    for (int r = 0; r < 4; ++r) l[r] = l[r] * resc[r] + psum[r];
#pragma unroll
    for (int dt = 0; dt < 4; ++dt)
#pragma unroll
      for (int r = 0; r < 4; ++r) accC[dt][r] *= resc[r];

#pragma unroll
    for (int ks = 0; ks < 4; ++ks)
#pragma unroll
      for (int r = 0; r < 4; ++r) {
        const int prow = w * 16 + g * 4 + r;
        const int pcol = ks * 16 + fr;
        Ps[prow * 64 + (pcol ^ ((prow & 7) << 3))] = fbits(S[ks][r]);
      }

#pragma unroll
    for (int kc = 0; kc < 2; ++kc) {
      const int prow = w * 16 + fr;
      const int k0 = kc * 32 + g * 8;
      short8 pf = *reinterpret_cast<const short8*>(&Ps[prow * 64 + (k0 ^ ((prow & 7) << 3))]);
#pragma unroll
      for (int dt = 0; dt < 4; ++dt) {
        const int dr = dt * 16 + fr;
        short8 vf = *reinterpret_cast<const short8*>(&VTs[dr * 64 + (k0 ^ ((dr & 7) << 3))]);
        accC[dt] = __builtin_amdgcn_mfma_f32_16x16x32_bf16(pf, vf, accC[dt], 0, 0, 0);
      }
    }
  }

  // ================= phase 3: gate mix + single write =================
#pragma unroll
  for (int r = 0; r < 4; ++r) {
    const int i = t0 + w * 16 + g * 4 + r;
    const float inv = (l[r] > 0.f) ? (1.f / l[r]) : 0.f;
#pragma unroll
    for (int dt = 0; dt < 4; ++dt) {
      const int d = dt * 16 + fr;
      const float yc = accC[dt][r] * inv;
      const float gg = b2f(gate[((size_t)(b * kT + i)) * kC + h * kHS + d]);
      ybuf[(size_t)i * kC + h * kHS + d] = f2b(gg * accL[dt][r] + (1.f - gg) * yc);
    }
  }
}

extern "C" void kernel_launch(void* const* d_in, const int* in_sizes, int n_in,
                              void* d_out, int out_size, void* d_ws, size_t ws_size,
                              hipStream_t stream)
{
  (void)in_sizes; (void)n_in; (void)out_size; (void)ws_size; (void)kM; (void)kWIN;
  const float* x      = (const float*)d_in[0];
  const float* Wqkv   = (const float*)d_in[1];
  const float* bqkv   = (const float*)d_in[2];
  const float* Wcomp  = (const float*)d_in[3];
  const float* bcomp  = (const float*)d_in[4];
  const float* Wproj  = (const float*)d_in[5];
  const float* bproj  = (const float*)d_in[6];
  const float* k_fc1W = (const float*)d_in[7];
  const float* k_fc1b = (const float*)d_in[8];
  const float* k_fc2W = (const float*)d_in[9];
  const float* k_fc2b = (const float*)d_in[10];
  const float* k_rpW  = (const float*)d_in[11];
  const float* k_rpb  = (const float*)d_in[12];
  const float* k_wpe  = (const float*)d_in[13];
  const float* v_fc1W = (const float*)d_in[14];
  const float* v_fc1b = (const float*)d_in[15];
  const float* v_fc2W = (const float*)d_in[16];
  const float* v_fc2b = (const float*)d_in[17];
  const float* v_rpW  = (const float*)d_in[18];
  const float* v_rpb  = (const float*)d_in[19];
  const float* v_wpe  = (const float*)d_in[20];
  const float* Wg1    = (const float*)d_in[21];
  const float* bg1    = (const float*)d_in[22];
  const float* Wg2    = (const float*)d_in[23];
  const float* bg2    = (const float*)d_in[24];

  // ---- Workspace (peak 51,372,032 B, identical to proven footprint) ----
  char* wsb = (char*)d_ws;
  bf16* xbf   = (bf16*)(wsb + 0);
  bf16* wscr  = (bf16*)(wsb + 8388608);
  bf16* big   = (bf16*)(wsb + 16777216);
  bf16* ybuf  = (bf16*)(wsb + 41943040);
  bf16* kcomp = (bf16*)(wsb + 50331648);
  bf16* vcomp = (bf16*)(wsb + 50851840);
  bf16* gate  = (bf16*)((char*)d_out + 8388608);
  float* out  = (float*)d_out;

  const int cg = 2048;
  f32_to_bf16<<<cg, 256, 0, stream>>>(x, xbf, 1048576);
  f32_to_bf16<<<cg, 256, 0, stream>>>(Wg1, wscr, 1048576);
  gemm_bf16<1, bf16><<<1024, 512, 0, stream>>>(xbf, wscr, bg1, big, 4096, 4096, 1024, 32);
  f32_to_bf16<<<cg, 256, 0, stream>>>(Wg2, wscr, 1048576);
  gemm_bf16_t64<3, bf16><<<1024, 256, 0, stream>>>(big, wscr, bg2, gate, 4096, 1024, 4096, 16);
  f32_to_bf16<<<cg, 256, 0, stream>>>(Wcomp, wscr, 524288);
  gemm_bf16<0, bf16><<<512, 512, 0, stream>>>(xbf, wscr, bcomp, big, 4096, 2048, 1024, 16);
  comp_mlp_mfma<<<dim3(kNB, kNH, kB * 2), 256, 0, stream>>>(
      big,
      k_fc1W, k_fc1b, k_fc2W, k_fc2b, k_rpW, k_rpb, k_wpe, kcomp,
      v_fc1W, v_fc1b, v_fc2W, v_fc2b, v_rpW, v_rpb, v_wpe, vcomp);
  f32_to_bf16<<<cg, 256, 0, stream>>>(Wqkv, wscr, 786432);
  gemm_bf16<0, bf16><<<768, 512, 0, stream>>>(xbf, wscr, bqkv, big, 4096, 3072, 1024, 24);
  f32_to_bf16<<<cg, 256, 0, stream>>>(Wproj, wscr, 262144);
  // fused attention (local + compressed + gate mix), QBLK=128, both batches
  fused_attn_mfma<<<dim3(kT / 128, kNH, kB), 512, 0, stream>>>(big, kcomp, vcomp, gate, ybuf);
  // single merged projection over both batches (overwrites gate region after use)
  gemm_bf16_t64<0, float><<<1024, 256, 0, stream>>>(ybuf, wscr, bproj, out, 4096, 1024, 1024, 16);
}

// Round 27
// 268.695 us; speedup vs baseline: 1.0495x; 1.0362x over previous
//
#include <hip/hip_runtime.h>
#include <hip/hip_bf16.h>

typedef __hip_bfloat16 bf16;

constexpr int kB = 2, kT = 2048, kC = 1024, kNH = 16, kHS = 64;
constexpr int kL = 32, kST = 16, kWIN = 256;
constexpr int kNB = (kT - kL) / kST + 1;   // 127
constexpr int kM = kB * kT;                // 4096

typedef __attribute__((ext_vector_type(8))) short short8;   // bf16 MFMA A/B frag (4 VGPRs)
typedef __attribute__((ext_vector_type(4))) short short4v;
typedef __attribute__((ext_vector_type(4))) float f32x4;

__device__ __forceinline__ float b2f(bf16 v) { return __bfloat162float(v); }
__device__ __forceinline__ bf16  f2b(float v) { return __float2bfloat16(v); }
__device__ __forceinline__ float bu2f(unsigned int u) { return __uint_as_float(u << 16); }
__device__ __forceinline__ float gelu_f(float v) { return 0.5f * v * (1.0f + erff(v * 0.70710678118654752f)); }
// branchless tanh-form GELU (max |err| vs exact ~3e-4); used only in comp_mlp
__device__ __forceinline__ float gelu_fast(float v) {
  const float w = v * (1.5957691216f + 0.0713548162f * v * v);   // 2*sqrt(2/pi)*(v+0.044715v^3)
  return v * __builtin_amdgcn_rcpf(1.0f + __expf(-w));           // v * sigmoid(w)
}
__device__ __forceinline__ short fbits(float v) {
  return (short)__builtin_bit_cast(unsigned short, f2b(v));
}
// async global->LDS, 16 bytes per lane (dest = wave-uniform base + lane*16)
__device__ __forceinline__ void gl16(const bf16* g, bf16* l) {
  __builtin_amdgcn_global_load_lds(
      (const __attribute__((address_space(1))) void*)g,
      (__attribute__((address_space(3))) void*)l, 16, 0, 0);
}

// ---------------- fp32 -> bf16 conversion (vectorized, grid-stride) ----------------
__global__ __launch_bounds__(256) void f32_to_bf16(const float* __restrict__ src,
                                                   bf16* __restrict__ dst, int n4) {
  int i = blockIdx.x * 256 + threadIdx.x;
  const int stride = gridDim.x * 256;
  for (; i < n4; i += stride) {
    float4 v = ((const float4*)src)[i];
    short4v w; w.x = fbits(v.x); w.y = fbits(v.y); w.z = fbits(v.z); w.w = fbits(v.w);
    ((short4v*)dst)[i] = w;
  }
}

// ---------------- all-bf16 MFMA GEMM: 128x128 tile, BK=64, 8 waves (2x4) [R23-proven] ----------------
template<int EPI, typename TY>
__global__ __launch_bounds__(512) void gemm_bf16(
    const bf16* __restrict__ X, const bf16* __restrict__ W,
    const float* __restrict__ bias, TY* __restrict__ Y,
    int M, int N, int K, int nbx)
{
  __shared__ __align__(16) bf16 As[128 * 64];
  __shared__ __align__(16) bf16 Bs[128 * 64];
  const int nwg = gridDim.x;
  const int bid = blockIdx.x;
  const int swz = (bid & 7) * (nwg >> 3) + (bid >> 3);
  const int bm = (swz / nbx) * 128;
  const int bn = (swz % nbx) * 128;
  const int tid = threadIdx.x;
  const int lane = tid & 63;
  const int w = tid >> 6;
  const int wr = w >> 2, wc = w & 3;      // 2x4 wave grid; wave tile 64 x 32
  const int fr = lane & 15, q = lane >> 4;
  const int srow = lane >> 3;
  const int scol = (lane & 7) * 8;

  f32x4 acc[4][2];
#pragma unroll
  for (int i = 0; i < 4; ++i)
#pragma unroll
    for (int j = 0; j < 2; ++j) acc[i][j] = (f32x4){0.f, 0.f, 0.f, 0.f};

  const bf16* Xb = X + (size_t)bm * K;
  const bf16* Wb = W + (size_t)bn * K;

  for (int k0 = 0; k0 < K; k0 += 64) {
    __syncthreads();
#pragma unroll
    for (int i = 0; i < 2; ++i) {
      const int r = w * 16 + i * 8 + srow;
      const int sc = scol ^ ((r & 7) << 3);   // pre-swizzled global source chunk
      gl16(Xb + (size_t)r * K + k0 + sc, &As[r * 64 + scol]);
      gl16(Wb + (size_t)r * K + k0 + sc, &Bs[r * 64 + scol]);
    }
    __syncthreads();
#pragma unroll
    for (int kk = 0; kk < 2; ++kk) {
      short8 af[4], bfr[2];
#pragma unroll
      for (int i = 0; i < 4; ++i) {
        const int ar = wr * 64 + i * 16 + fr;
        af[i] = *reinterpret_cast<const short8*>(&As[ar * 64 + ((kk * 32 + q * 8) ^ ((ar & 7) << 3))]);
      }
#pragma unroll
      for (int j = 0; j < 2; ++j) {
        const int br = wc * 32 + j * 16 + fr;
        bfr[j] = *reinterpret_cast<const short8*>(&Bs[br * 64 + ((kk * 32 + q * 8) ^ ((br & 7) << 3))]);
      }
#pragma unroll
      for (int i = 0; i < 4; ++i)
#pragma unroll
        for (int j = 0; j < 2; ++j)
          acc[i][j] = __builtin_amdgcn_mfma_f32_16x16x32_bf16(af[i], bfr[j], acc[i][j], 0, 0, 0);
    }
  }

#pragma unroll
  for (int j = 0; j < 2; ++j) {
    const int gcol = bn + wc * 32 + j * 16 + fr;
    const float bv = bias[gcol];
#pragma unroll
    for (int i = 0; i < 4; ++i) {
      const int grow0 = bm + wr * 64 + i * 16 + q * 4;
#pragma unroll
      for (int r = 0; r < 4; ++r) {
        float v = acc[i][j][r] + bv;
        if (EPI == 1) v = gelu_f(v);
        if (EPI == 3) v = 1.f / (1.f + expf(-v));
        if constexpr (sizeof(TY) == 2) Y[(size_t)(grow0 + r) * N + gcol] = f2b(v);
        else                           ((float*)Y)[(size_t)(grow0 + r) * N + gcol] = v;
      }
    }
  }
}

// ---------------- small-tile GEMM: 64x64 tile, BK=64, 4 waves (2x2) [R24-proven] ----------------
template<int EPI, typename TY>
__global__ __launch_bounds__(256) void gemm_bf16_t64(
    const bf16* __restrict__ X, const bf16* __restrict__ W,
    const float* __restrict__ bias, TY* __restrict__ Y,
    int M, int N, int K, int nbx)
{
  __shared__ __align__(16) bf16 As[64 * 64];
  __shared__ __align__(16) bf16 Bs[64 * 64];
  const int nwg = gridDim.x;
  const int bid = blockIdx.x;
  const int swz = (bid & 7) * (nwg >> 3) + (bid >> 3);
  const int bm = (swz / nbx) * 64;
  const int bn = (swz % nbx) * 64;
  const int tid = threadIdx.x;
  const int lane = tid & 63;
  const int w = tid >> 6;                 // 0..3
  const int wr = w >> 1, wc = w & 1;      // 2x2 wave grid; wave tile 32 x 32
  const int fr = lane & 15, q = lane >> 4;
  const int srow = lane >> 3;
  const int scol = (lane & 7) * 8;

  f32x4 acc[2][2];
#pragma unroll
  for (int i = 0; i < 2; ++i)
#pragma unroll
    for (int j = 0; j < 2; ++j) acc[i][j] = (f32x4){0.f, 0.f, 0.f, 0.f};

  const bf16* Xb = X + (size_t)bm * K;
  const bf16* Wb = W + (size_t)bn * K;

  for (int k0 = 0; k0 < K; k0 += 64) {
    __syncthreads();
#pragma unroll
    for (int i = 0; i < 2; ++i) {        // wave w stages rows [w*16, w*16+16) of A and B
      const int r = w * 16 + i * 8 + srow;
      const int sc = scol ^ ((r & 7) << 3);
      gl16(Xb + (size_t)r * K + k0 + sc, &As[r * 64 + scol]);
      gl16(Wb + (size_t)r * K + k0 + sc, &Bs[r * 64 + scol]);
    }
    __syncthreads();
#pragma unroll
    for (int kk = 0; kk < 2; ++kk) {
      short8 af[2], bfr[2];
#pragma unroll
      for (int i = 0; i < 2; ++i) {
        const int ar = wr * 32 + i * 16 + fr;
        af[i] = *reinterpret_cast<const short8*>(&As[ar * 64 + ((kk * 32 + q * 8) ^ ((ar & 7) << 3))]);
      }
#pragma unroll
      for (int j = 0; j < 2; ++j) {
        const int br = wc * 32 + j * 16 + fr;
        bfr[j] = *reinterpret_cast<const short8*>(&Bs[br * 64 + ((kk * 32 + q * 8) ^ ((br & 7) << 3))]);
      }
#pragma unroll
      for (int i = 0; i < 2; ++i)
#pragma unroll
        for (int j = 0; j < 2; ++j)
          acc[i][j] = __builtin_amdgcn_mfma_f32_16x16x32_bf16(af[i], bfr[j], acc[i][j], 0, 0, 0);
    }
  }

#pragma unroll
  for (int j = 0; j < 2; ++j) {
    const int gcol = bn + wc * 32 + j * 16 + fr;
    const float bv = bias[gcol];
#pragma unroll
    for (int i = 0; i < 2; ++i) {
      const int grow0 = bm + wr * 32 + i * 16 + q * 4;
#pragma unroll
      for (int r = 0; r < 4; ++r) {
        float v = acc[i][j][r] + bv;
        if (EPI == 1) v = gelu_f(v);
        if (EPI == 3) v = 1.f / (1.f + expf(-v));
        if constexpr (sizeof(TY) == 2) Y[(size_t)(grow0 + r) * N + gcol] = f2b(v);
        else                           ((float*)Y)[(size_t)(grow0 + r) * N + gcol] = v;
      }
    }
  }
}

// ---------------- Compression MLP via MFMA (R22-proven: gelu_fast) ----------------
__global__ __launch_bounds__(256) void comp_mlp_mfma(
    const bf16* __restrict__ kvbuf,
    const float* __restrict__ k_fc1W, const float* __restrict__ k_fc1b,
    const float* __restrict__ k_fc2W, const float* __restrict__ k_fc2b,
    const float* __restrict__ k_rpW,  const float* __restrict__ k_rpb,
    const float* __restrict__ k_wpe,  bf16* __restrict__ k_out,
    const float* __restrict__ v_fc1W, const float* __restrict__ v_fc1b,
    const float* __restrict__ v_fc2W, const float* __restrict__ v_fc2b,
    const float* __restrict__ v_rpW,  const float* __restrict__ v_rpb,
    const float* __restrict__ v_wpe,  bf16* __restrict__ v_out)
{
  __shared__ __align__(16) short XPE[64 * 40];
  __shared__ __align__(16) short XU [64 * 40];
  __shared__ __align__(16) short FC1[128 * 40];
  __shared__ float s_fc1b[128];
  __shared__ float s_fc2W[128];
  __shared__ float s_rpW[32];
  const int tid = threadIdx.x;
  const int lane = tid & 63;
  const int w = tid >> 6;
  const int fr = lane & 15, q = lane >> 4;
  const int blk = blockIdx.x;
  const int h = blockIdx.y;
  const int s = blockIdx.z & 1;
  const int b = blockIdx.z >> 1;
  const int t0 = blk * kST;
  const float* fc1W = s ? v_fc1W : k_fc1W;
  const float* fc1b = s ? v_fc1b : k_fc1b;
  const float* fc2W = s ? v_fc2W : k_fc2W;
  const float* fc2b = s ? v_fc2b : k_fc2b;
  const float* rpW  = s ? v_rpW  : k_rpW;
  const float* rpb  = s ? v_rpb  : k_rpb;
  const float* wpe  = s ? v_wpe  : k_wpe;
  bf16* outp        = s ? v_out  : k_out;

  {
    const int base = tid * 16;
#pragma unroll
    for (int c = 0; c < 4; ++c) {
      float4 v = *reinterpret_cast<const float4*>(fc1W + base + c * 4);
      const int idx = base + c * 4;
      short* dst = &FC1[(idx >> 5) * 40 + (idx & 31)];
      dst[0] = fbits(v.x); dst[1] = fbits(v.y); dst[2] = fbits(v.z); dst[3] = fbits(v.w);
    }
  }
  if (tid < 128) { s_fc1b[tid] = fc1b[tid]; s_fc2W[tid] = fc2W[tid]; }
  else if (tid < 160) s_rpW[tid - 128] = rpW[tid - 128];
  {
    const int l = tid >> 3, d0 = (tid & 7) * 8;
    const bf16* src = kvbuf + ((size_t)(b * kT + t0 + l) * (2 * kC)) + (size_t)s * kC + h * kHS + d0;
    short8 u = *reinterpret_cast<const short8*>(src);
    const float* wp = wpe + l * kHS + d0;
#pragma unroll
    for (int e = 0; e < 8; ++e) {
      const int d = d0 + e;
      XU[d * 40 + l] = u[e];
      const float xv = bu2f((unsigned short)u[e]) + wp[e];
      XPE[d * 40 + l] = fbits(xv);
    }
  }
  __syncthreads();

  const short8 af = *reinterpret_cast<const short8*>(&XPE[(w * 16 + fr) * 40 + q * 8]);
  f32x4 acc[8];
#pragma unroll
  for (int nt = 0; nt < 8; ++nt) {
    const short8 bf_ = *reinterpret_cast<const short8*>(&FC1[(nt * 16 + fr) * 40 + q * 8]);
    acc[nt] = __builtin_amdgcn_mfma_f32_16x16x32_bf16(af, bf_, (f32x4){0.f, 0.f, 0.f, 0.f}, 0, 0, 0);
  }

  float sum[4] = {0.f, 0.f, 0.f, 0.f};
#pragma unroll
  for (int nt = 0; nt < 8; ++nt) {
    const int j = nt * 16 + fr;
    const float bb = s_fc1b[j];
    const float w2 = s_fc2W[j];
#pragma unroll
    for (int r = 0; r < 4; ++r)
      sum[r] += gelu_fast(acc[nt][r] + bb) * w2;
  }
#pragma unroll
  for (int r = 0; r < 4; ++r) {
    const int d = w * 16 + q * 4 + r;
#pragma unroll
    for (int e = 0; e < 2; ++e) {
      const int l = fr * 2 + e;
      sum[r] += bu2f((unsigned short)XU[d * 40 + l]) * s_rpW[l];
    }
  }
#pragma unroll
  for (int off = 1; off <= 8; off <<= 1)
#pragma unroll
    for (int r = 0; r < 4; ++r) sum[r] += __shfl_xor(sum[r], off);

  if (fr == 0) {
    const float c0 = fc2b[0] + rpb[0];
    bf16* op = outp + ((size_t)(b * kNH + h) * kNB + blk) * kHS;
#pragma unroll
    for (int r = 0; r < 4; ++r) {
      float v = sum[r] + c0;
      v = fminf(3.0f, fmaxf(-3.0f, v));
      op[w * 16 + q * 4 + r] = f2b(v);
    }
  }
}

// ---------------- FUSED attention, QBLK=128, XCD-chunked grid ----------------
// 1-D grid of 512 blocks; XCD (flat&7) gets 64 consecutive swz = all 16 q-tiles
// x 4 heads for one batch -> K/V window overlap stays L2-resident per XCD.
__global__ __launch_bounds__(512) void fused_attn_mfma(
    const bf16* __restrict__ qkv, const bf16* __restrict__ kcomp,
    const bf16* __restrict__ vcomp, const bf16* __restrict__ gate,
    bf16* __restrict__ ybuf0)
{
  __shared__ __align__(16) short Qs[128 * 64];
  __shared__ __align__(16) short Ks[64 * 64];
  __shared__ __align__(16) short VTs[64 * 64];
  __shared__ __align__(16) short Ps[128 * 64];
  const int tid = threadIdx.x;
  const int lane = tid & 63;
  const int w = tid >> 6;                 // 0..7; wave owns q rows [w*16, w*16+16)
  const int fr = lane & 15;
  const int g  = lane >> 4;
  const int flat = blockIdx.x;            // 0..511
  const int swzb = (flat & 7) * 64 + (flat >> 3);   // bijective XCD chunking
  const int h  = (swzb >> 4) & 15;
  const int b  = swzb >> 8;
  const int t0 = (swzb & 15) * 128;
  bf16* ybuf = ybuf0 + (size_t)b * kT * kC;
  const size_t rs = 3 * kC;
  const bf16* qbase = qkv + ((size_t)b * kT) * rs + h * kHS;
  const bf16* kbase = qbase + kC;
  const bf16* vbase = qbase + 2 * kC;
  const bf16* kb = kcomp + ((size_t)(b * kNH + h)) * kNB * kHS;
  const bf16* vb = vcomp + ((size_t)(b * kNH + h)) * kNB * kHS;

  // stage Q once (128 rows)
  for (int c = tid; c < 1024; c += 512) {
    const int r = c >> 3, p = c & 7;
    short8 v = *reinterpret_cast<const short8*>(qbase + (size_t)(t0 + r) * rs + p * 8);
    *reinterpret_cast<short8*>(&Qs[r * 64 + ((p ^ (r & 7)) << 3)]) = v;
  }
  __syncthreads();
  short8 qf[2];
  {
    const int r = w * 16 + fr;
#pragma unroll
    for (int dc = 0; dc < 2; ++dc) {
      const int d0 = dc * 32 + g * 8;
      qf[dc] = *reinterpret_cast<const short8*>(&Qs[r * 64 + (d0 ^ ((r & 7) << 3))]);
    }
  }
  const int qrow0 = t0 + w * 16 + g * 4;

  // ================= phase 1: local sliding-window attention =================
  f32x4 accL[4];
  float m[4], l[4];
#pragma unroll
  for (int r = 0; r < 4; ++r) { m[r] = -1e30f; l[r] = 0.f; }
#pragma unroll
  for (int dt = 0; dt < 4; ++dt) accL[dt] = (f32x4){0.f, 0.f, 0.f, 0.f};

  const int jb0 = (t0 >= 256) ? (t0 - 256) : 0;
  for (int jb = jb0; jb <= t0 + 64; jb += 64) {
    // fully-valid tiles for all 128 rows: jb in [t0-128, t0-64]
    const bool masked = !((jb >= t0 - 128) && (jb <= t0 - 64));
    __syncthreads();
    for (int c = tid; c < 512; c += 512) {
      const int r = c >> 3, p = c & 7;
      short8 v = *reinterpret_cast<const short8*>(kbase + (size_t)(jb + r) * rs + p * 8);
      *reinterpret_cast<short8*>(&Ks[r * 64 + ((p ^ (r & 7)) << 3)]) = v;
    }
    for (int c = tid; c < 512; c += 512) {
      const int r = c >> 3, p = c & 7;
      short8 v = *reinterpret_cast<const short8*>(vbase + (size_t)(jb + r) * rs + p * 8);
#pragma unroll
      for (int e = 0; e < 8; ++e) {
        const int d = p * 8 + e;
        VTs[d * 64 + (r ^ ((d & 7) << 3))] = v[e];
      }
    }
    __syncthreads();

    f32x4 S[4];
#pragma unroll
    for (int ks = 0; ks < 4; ++ks) S[ks] = (f32x4){0.f, 0.f, 0.f, 0.f};
#pragma unroll
    for (int ks = 0; ks < 4; ++ks) {
      const int kr = ks * 16 + fr;
#pragma unroll
      for (int dc = 0; dc < 2; ++dc) {
        const int d0 = dc * 32 + g * 8;
        short8 kf = *reinterpret_cast<const short8*>(&Ks[kr * 64 + (d0 ^ ((kr & 7) << 3))]);
        S[ks] = __builtin_amdgcn_mfma_f32_16x16x32_bf16(qf[dc], kf, S[ks], 0, 0, 0);
      }
    }

    float rowmax[4];
#pragma unroll
    for (int r = 0; r < 4; ++r) rowmax[r] = -1e30f;
#pragma unroll
    for (int ks = 0; ks < 4; ++ks) {
      const int j = jb + ks * 16 + fr;
#pragma unroll
      for (int r = 0; r < 4; ++r) {
        float s = S[ks][r] * 0.125f;
        if (masked) {
          const int i = qrow0 + r;
          if (!((j <= i) && (j > i - 256))) s = -1e30f;
        }
        S[ks][r] = s;
        rowmax[r] = fmaxf(rowmax[r], s);
      }
    }
#pragma unroll
    for (int off = 1; off <= 8; off <<= 1)
#pragma unroll
      for (int r = 0; r < 4; ++r)
        rowmax[r] = fmaxf(rowmax[r], __shfl_xor(rowmax[r], off));

    float resc[4], psum[4];
#pragma unroll
    for (int r = 0; r < 4; ++r) {
      const float mn = fmaxf(m[r], rowmax[r]);
      resc[r] = __expf(m[r] - mn);
      m[r] = mn;
      psum[r] = 0.f;
    }
#pragma unroll
    for (int ks = 0; ks < 4; ++ks) {
      const int j = jb + ks * 16 + fr;
#pragma unroll
      for (int r = 0; r < 4; ++r) {
        float p = __expf(S[ks][r] - m[r]);
        if (masked) {
          const int i = qrow0 + r;
          if (!((j <= i) && (j > i - 256))) p = 0.f;
        }
        S[ks][r] = p;
        psum[r] += p;
      }
    }
#pragma unroll
    for (int off = 1; off <= 8; off <<= 1)
#pragma unroll
      for (int r = 0; r < 4; ++r) psum[r] += __shfl_xor(psum[r], off);
#pragma unroll
    for (int r = 0; r < 4; ++r) l[r] = l[r] * resc[r] + psum[r];
#pragma unroll
    for (int dt = 0; dt < 4; ++dt)
#pragma unroll
      for (int r = 0; r < 4; ++r) accL[dt][r] *= resc[r];

#pragma unroll
    for (int ks = 0; ks < 4; ++ks)
#pragma unroll
      for (int r = 0; r < 4; ++r) {
        const int prow = w * 16 + g * 4 + r;
        const int pcol = ks * 16 + fr;
        Ps[prow * 64 + (pcol ^ ((prow & 7) << 3))] = fbits(S[ks][r]);
      }

#pragma unroll
    for (int kc = 0; kc < 2; ++kc) {
      const int prow = w * 16 + fr;
      const int k0 = kc * 32 + g * 8;
      short8 pf = *reinterpret_cast<const short8*>(&Ps[prow * 64 + (k0 ^ ((prow & 7) << 3))]);
#pragma unroll
      for (int dt = 0; dt < 4; ++dt) {
        const int dr = dt * 16 + fr;
        short8 vf = *reinterpret_cast<const short8*>(&VTs[dr * 64 + (k0 ^ ((dr & 7) << 3))]);
        accL[dt] = __builtin_amdgcn_mfma_f32_16x16x32_bf16(pf, vf, accL[dt], 0, 0, 0);
      }
    }
  }
  // finalize local: accL now holds yl
#pragma unroll
  for (int dt = 0; dt < 4; ++dt)
#pragma unroll
    for (int r = 0; r < 4; ++r) accL[dt][r] /= l[r];

  // ================= phase 2: compressed-block attention =================
  f32x4 accC[4];
#pragma unroll
  for (int r = 0; r < 4; ++r) { m[r] = -1e30f; l[r] = 0.f; }
#pragma unroll
  for (int dt = 0; dt < 4; ++dt) accC[dt] = (f32x4){0.f, 0.f, 0.f, 0.f};

  const int ntiles = ((t0 + 126) >> 10) + 1;   // 1 or 2 tiles of 64 key blocks
  for (int tb = 0; tb < ntiles; ++tb) {
    const int jb = tb * 64;
    const bool masked = !(((jb + 63) < kNB) && ((jb + 63) * kST < t0));
    __syncthreads();
    for (int c = tid; c < 512; c += 512) {
      const int r = c >> 3, p = c & 7;
      const int rr = (jb + r < kNB) ? (jb + r) : (kNB - 1);
      short8 v = *reinterpret_cast<const short8*>(kb + (size_t)rr * kHS + p * 8);
      *reinterpret_cast<short8*>(&Ks[r * 64 + ((p ^ (r & 7)) << 3)]) = v;
    }
    for (int c = tid; c < 512; c += 512) {
      const int r = c >> 3, p = c & 7;
      const int rr = (jb + r < kNB) ? (jb + r) : (kNB - 1);
      short8 v = *reinterpret_cast<const short8*>(vb + (size_t)rr * kHS + p * 8);
#pragma unroll
      for (int e = 0; e < 8; ++e) {
        const int d = p * 8 + e;
        VTs[d * 64 + (r ^ ((d & 7) << 3))] = v[e];
      }
    }
    __syncthreads();

    f32x4 S[4];
#pragma unroll
    for (int ks = 0; ks < 4; ++ks) S[ks] = (f32x4){0.f, 0.f, 0.f, 0.f};
#pragma unroll
    for (int ks = 0; ks < 4; ++ks) {
      const int kr = ks * 16 + fr;
#pragma unroll
      for (int dc = 0; dc < 2; ++dc) {
        const int d0 = dc * 32 + g * 8;
        short8 kf = *reinterpret_cast<const short8*>(&Ks[kr * 64 + (d0 ^ ((kr & 7) << 3))]);
        S[ks] = __builtin_amdgcn_mfma_f32_16x16x32_bf16(qf[dc], kf, S[ks], 0, 0, 0);
      }
    }

    float rowmax[4];
#pragma unroll
    for (int r = 0; r < 4; ++r) rowmax[r] = -1e30f;
#pragma unroll
    for (int ks = 0; ks < 4; ++ks) {
      const int n = jb + ks * 16 + fr;
#pragma unroll
      for (int r = 0; r < 4; ++r) {
        float s = S[ks][r] * 0.125f;
        if (masked) {
          const int i = qrow0 + r;
          if (!((n < kNB) && (n * kST < i))) s = -1e30f;
        }
        S[ks][r] = s;
        rowmax[r] = fmaxf(rowmax[r], s);
      }
    }
#pragma unroll
    for (int off = 1; off <= 8; off <<= 1)
#pragma unroll
      for (int r = 0; r < 4; ++r)
        rowmax[r] = fmaxf(rowmax[r], __shfl_xor(rowmax[r], off));

    float resc[4], psum[4];
#pragma unroll
    for (int r = 0; r < 4; ++r) {
      const float mn = fmaxf(m[r], rowmax[r]);
      resc[r] = __expf(m[r] - mn);
      m[r] = mn;
      psum[r] = 0.f;
    }
#pragma unroll
    for (int ks = 0; ks < 4; ++ks) {
      const int n = jb + ks * 16 + fr;
#pragma unroll
      for (int r = 0; r < 4; ++r) {
        float p = __expf(S[ks][r] - m[r]);
        if (masked) {
          const int i = qrow0 + r;
          if (!((n < kNB) && (n * kST < i))) p = 0.f;
        }
        S[ks][r] = p;
        psum[r] += p;
      }
    }
#pragma unroll
    for (int off = 1; off <= 8; off <<= 1)
#pragma unroll
      for (int r = 0; r < 4; ++r) psum[r] += __shfl_xor(psum[r], off);
#pragma unroll
    for (int r = 0; r < 4; ++r) l[r] = l[r] * resc[r] + psum[r];
#pragma unroll
    for (int dt = 0; dt < 4; ++dt)
#pragma unroll
      for (int r = 0; r < 4; ++r) accC[dt][r] *= resc[r];

#pragma unroll
    for (int ks = 0; ks < 4; ++ks)
#pragma unroll
      for (int r = 0; r < 4; ++r) {
        const int prow = w * 16 + g * 4 + r;
        const int pcol = ks * 16 + fr;
        Ps[prow * 64 + (pcol ^ ((prow & 7) << 3))] = fbits(S[ks][r]);
      }

#pragma unroll
    for (int kc = 0; kc < 2; ++kc) {
      const int prow = w * 16 + fr;
      const int k0 = kc * 32 + g * 8;
      short8 pf = *reinterpret_cast<const short8*>(&Ps[prow * 64 + (k0 ^ ((prow & 7) << 3))]);
#pragma unroll
      for (int dt = 0; dt < 4; ++dt) {
        const int dr = dt * 16 + fr;
        short8 vf = *reinterpret_cast<const short8*>(&VTs[dr * 64 + (k0 ^ ((dr & 7) << 3))]);
        accC[dt] = __builtin_amdgcn_mfma_f32_16x16x32_bf16(pf, vf, accC[dt], 0, 0, 0);
      }
    }
  }

  // ================= phase 3: gate mix + single write =================
#pragma unroll
  for (int r = 0; r < 4; ++r) {
    const int i = t0 + w * 16 + g * 4 + r;
    const float inv = (l[r] > 0.f) ? (1.f / l[r]) : 0.f;
#pragma unroll
    for (int dt = 0; dt < 4; ++dt) {
      const int d = dt * 16 + fr;
      const float yc = accC[dt][r] * inv;
      const float gg = b2f(gate[((size_t)(b * kT + i)) * kC + h * kHS + d]);
      ybuf[(size_t)i * kC + h * kHS + d] = f2b(gg * accL[dt][r] + (1.f - gg) * yc);
    }
  }
}

extern "C" void kernel_launch(void* const* d_in, const int* in_sizes, int n_in,
                              void* d_out, int out_size, void* d_ws, size_t ws_size,
                              hipStream_t stream)
{
  (void)in_sizes; (void)n_in; (void)out_size; (void)ws_size; (void)kM; (void)kWIN;
  const float* x      = (const float*)d_in[0];
  const float* Wqkv   = (const float*)d_in[1];
  const float* bqkv   = (const float*)d_in[2];
  const float* Wcomp  = (const float*)d_in[3];
  const float* bcomp  = (const float*)d_in[4];
  const float* Wproj  = (const float*)d_in[5];
  const float* bproj  = (const float*)d_in[6];
  const float* k_fc1W = (const float*)d_in[7];
  const float* k_fc1b = (const float*)d_in[8];
  const float* k_fc2W = (const float*)d_in[9];
  const float* k_fc2b = (const float*)d_in[10];
  const float* k_rpW  = (const float*)d_in[11];
  const float* k_rpb  = (const float*)d_in[12];
  const float* k_wpe  = (const float*)d_in[13];
  const float* v_fc1W = (const float*)d_in[14];
  const float* v_fc1b = (const float*)d_in[15];
  const float* v_fc2W = (const float*)d_in[16];
  const float* v_fc2b = (const float*)d_in[17];
  const float* v_rpW  = (const float*)d_in[18];
  const float* v_rpb  = (const float*)d_in[19];
  const float* v_wpe  = (const float*)d_in[20];
  const float* Wg1    = (const float*)d_in[21];
  const float* bg1    = (const float*)d_in[22];
  const float* Wg2    = (const float*)d_in[23];
  const float* bg2    = (const float*)d_in[24];

  // ---- Workspace (peak 51,372,032 B, identical to proven footprint) ----
  char* wsb = (char*)d_ws;
  bf16* xbf   = (bf16*)(wsb + 0);
  bf16* wscr  = (bf16*)(wsb + 8388608);
  bf16* big   = (bf16*)(wsb + 16777216);
  bf16* ybuf  = (bf16*)(wsb + 41943040);
  bf16* kcomp = (bf16*)(wsb + 50331648);
  bf16* vcomp = (bf16*)(wsb + 50851840);
  bf16* gate  = (bf16*)((char*)d_out + 8388608);
  float* out  = (float*)d_out;

  const int cg = 2048;
  f32_to_bf16<<<cg, 256, 0, stream>>>(x, xbf, 1048576);
  f32_to_bf16<<<cg, 256, 0, stream>>>(Wg1, wscr, 1048576);
  gemm_bf16<1, bf16><<<1024, 512, 0, stream>>>(xbf, wscr, bg1, big, 4096, 4096, 1024, 32);
  f32_to_bf16<<<cg, 256, 0, stream>>>(Wg2, wscr, 1048576);
  gemm_bf16_t64<3, bf16><<<1024, 256, 0, stream>>>(big, wscr, bg2, gate, 4096, 1024, 4096, 16);
  f32_to_bf16<<<cg, 256, 0, stream>>>(Wcomp, wscr, 524288);
  gemm_bf16<0, bf16><<<512, 512, 0, stream>>>(xbf, wscr, bcomp, big, 4096, 2048, 1024, 16);
  comp_mlp_mfma<<<dim3(kNB, kNH, kB * 2), 256, 0, stream>>>(
      big,
      k_fc1W, k_fc1b, k_fc2W, k_fc2b, k_rpW, k_rpb, k_wpe, kcomp,
      v_fc1W, v_fc1b, v_fc2W, v_fc2b, v_rpW, v_rpb, v_wpe, vcomp);
  f32_to_bf16<<<cg, 256, 0, stream>>>(Wqkv, wscr, 786432);
  gemm_bf16<0, bf16><<<768, 512, 0, stream>>>(xbf, wscr, bqkv, big, 4096, 3072, 1024, 24);
  f32_to_bf16<<<cg, 256, 0, stream>>>(Wproj, wscr, 262144);
  // fused attention (local + compressed + gate mix), QBLK=128, XCD-chunked 1-D grid
  fused_attn_mfma<<<512, 512, 0, stream>>>(big, kcomp, vcomp, gate, ybuf);
  // single merged projection over both batches (overwrites gate region after use)
  gemm_bf16_t64<0, float><<<1024, 256, 0, stream>>>(ybuf, wscr, bproj, out, 4096, 1024, 1024, 16);
}